// Round 15
// baseline (434.924 us; speedup 1.0000x reference)
//
#include <hip/hip_runtime.h>

#define DIM 64
#define BIN_SHIFT 8          // 256 nodes per bin
#define BCAP 5120            // staging capacity per bin (mean 4092, +16 sigma)

typedef __attribute__((ext_vector_type(8))) _Float16 half8;
typedef __attribute__((ext_vector_type(4))) _Float16 half4;
typedef __attribute__((ext_vector_type(4))) float floatx4;

// ---------------------------------------------------------------------------
// Pass A: bin edges by col>>8. In-block counting sort by bin in LDS, then
// bin-sorted readout -> contiguous store runs per bin segment.
// ---------------------------------------------------------------------------
__launch_bounds__(256)
__global__ void bin_edges_kernel(const int* __restrict__ row,
                                 const int* __restrict__ col,
                                 int* __restrict__ bin_cursor,
                                 int2* __restrict__ staging, int E) {
    __shared__ int hist[512];
    __shared__ int offs[512];
    __shared__ int base[512];
    __shared__ int s[256];
    __shared__ int2 buf[4096];
    int tid = threadIdx.x;
    for (int i = tid; i < 512; i += 256) hist[i] = 0;
    __syncthreads();
    int e0 = blockIdx.x * 4096;
    int c[16], r[16];
    #pragma unroll
    for (int k = 0; k < 16; ++k) {
        int e = e0 + tid + k * 256;
        c[k] = (e < E) ? col[e] : -1;
        r[k] = (e < E) ? row[e] : 0;
        if (c[k] >= 0) atomicAdd(&hist[c[k] >> BIN_SHIFT], 1);
    }
    __syncthreads();
    // exclusive scan of hist[512] via pair-sums + Hillis-Steele over 256
    int h0 = hist[2 * tid], h1 = hist[2 * tid + 1];
    int ps = h0 + h1;
    s[tid] = ps;
    __syncthreads();
    for (int d = 1; d < 256; d <<= 1) {
        int v = (tid >= d) ? s[tid - d] : 0;
        __syncthreads();
        s[tid] += v;
        __syncthreads();
    }
    int ex = s[tid] - ps;
    offs[2 * tid] = ex;
    offs[2 * tid + 1] = ex + h0;
    __syncthreads();
    // global reservation per bin; reset hist for use as scatter cursor
    for (int i = tid; i < 512; i += 256) {
        base[i] = (hist[i] > 0) ? atomicAdd(&bin_cursor[i], hist[i]) : 0;
        hist[i] = 0;
    }
    __syncthreads();
    // scatter into bin-sorted LDS buffer
    #pragma unroll
    for (int k = 0; k < 16; ++k) {
        if (c[k] >= 0) {
            int b = c[k] >> BIN_SHIFT;
            int pos = offs[b] + atomicAdd(&hist[b], 1);
            buf[pos] = make_int2(r[k], c[k]);
        }
    }
    __syncthreads();
    // linear readout: adjacent lanes -> adjacent buf -> contiguous store runs
    int count = (e0 + 4096 <= E) ? 4096 : (E > e0 ? E - e0 : 0);
    for (int i = tid; i < count; i += 256) {
        int2 rc = buf[i];
        int b = rc.y >> BIN_SHIFT;
        staging[(size_t)b * BCAP + base[b] + (i - offs[b])] = rc;
    }
}

// ---------------------------------------------------------------------------
// Per-bin degree count + dinv/rdinv + padded chunk sum bs[b].
// pdeg = (deg+1+3)&~3  (self-edge included, pad to groups of 4).
// ---------------------------------------------------------------------------
__launch_bounds__(256)
__global__ void count_deg_bins_kernel(const int2* __restrict__ staging,
                                      const int* __restrict__ bin_cursor,
                                      int* __restrict__ deg,
                                      float* __restrict__ dinv,
                                      float* __restrict__ rdinv,
                                      int* __restrict__ bs, int N) {
    __shared__ int hist[256];
    __shared__ int red[256];
    int b = blockIdx.x;
    int tid = threadIdx.x;
    hist[tid] = 0;
    __syncthreads();
    int cnt = bin_cursor[b];
    for (int i = tid; i < cnt; i += 256)
        atomicAdd(&hist[staging[(size_t)b * BCAP + i].y & 255], 1);
    __syncthreads();
    int n = (b << BIN_SHIFT) + tid;
    int pdeg = 0;
    if (n < N) {
        int dg = hist[tid];
        deg[n] = dg;
        float d = (float)dg + 1.0f;
        dinv[n] = rsqrtf(d);
        rdinv[n] = sqrtf(d);
        pdeg = (dg + 1 + 3) & ~3;
    }
    red[tid] = pdeg;
    __syncthreads();
    for (int d = 128; d > 0; d >>= 1) {
        if (tid < d) red[tid] += red[tid + d];
        __syncthreads();
    }
    if (tid == 0) bs[b] = red[0];
}

__global__ void scan_block_sums_kernel(int* __restrict__ bs, int nb) {
    __shared__ int s[1024];
    int t = threadIdx.x;
    s[t] = (t < nb) ? bs[t] : 0;
    __syncthreads();
    for (int d = 1; d < 1024; d <<= 1) {
        int v = (t >= d) ? s[t - d] : 0;
        __syncthreads();
        s[t] += v;
        __syncthreads();
    }
    if (t < nb) bs[t] = (t == 0) ? 0 : s[t - 1];
}

__global__ void scan_chunks_kernel(const int* __restrict__ deg,
                                   const int* __restrict__ bs,
                                   int* __restrict__ ptr, int N) {
    __shared__ int s[256];
    int b = blockIdx.x, t = threadIdx.x;
    int i = b * 256 + t;
    int v = (i < N) ? ((deg[i] + 1 + 3) & ~3) : 0;
    s[t] = v;
    __syncthreads();
    for (int d = 1; d < 256; d <<= 1) {
        int u = (t >= d) ? s[t - d] : 0;
        __syncthreads();
        s[t] += u;
        __syncthreads();
    }
    if (i < N) {
        int p = bs[b] + s[t] - v;
        ptr[i] = p;
        if (i == N - 1) ptr[N] = p + v;
    }
}

// ---------------------------------------------------------------------------
// Pass B: one block per bin; LDS cursors. Bucket = self-edge n, in-edges,
// dummy-N padding to x4. Last block also fills the 64-int srcs tail pad with
// dummy (spmv speculatively preloads group indices up to beg+23).
// ---------------------------------------------------------------------------
__launch_bounds__(256)
__global__ void fill_bins_kernel(const int2* __restrict__ staging,
                                 const int* __restrict__ bin_cursor,
                                 const int* __restrict__ ptr,
                                 int* __restrict__ srcs, int N, int dummy) {
    __shared__ int cur[256];
    int b = blockIdx.x;
    int tid = threadIdx.x;
    int n = (b << BIN_SHIFT) + tid;
    if (n < N) {
        int p = ptr[n];
        srcs[p] = n;           // self-edge
        cur[tid] = p + 1;
    } else cur[tid] = 0;
    if (b == gridDim.x - 1 && tid < 64)
        srcs[ptr[N] + tid] = dummy;      // tail pad: valid (zero) row ids
    __syncthreads();
    int cnt = bin_cursor[b];
    for (int i = tid; i < cnt; i += 256) {
        int2 rc = staging[(size_t)b * BCAP + i];
        int pos = atomicAdd(&cur[rc.y & 255], 1);
        srcs[pos] = rc.x;
    }
    __syncthreads();
    if (n < N) {
        int e = cur[tid];            // == ptr[n] + 1 + deg[n]
        int stop = ptr[n + 1];
        for (; e < stop; ++e) srcs[e] = dummy;
    }
}

// ---------------------------------------------------------------------------
// scale_init: v0 (slab-major fp16 = dinv*x, 4 slabs of 16 halves = 32B rows),
// x16 (row-major fp16), dummy-row zeroing for all 6 slab buffers.
// Slab S = d>>4, row n at (S*(N+1)+n)*16.
// ---------------------------------------------------------------------------
__global__ void scale_init_slab_kernel(const float* __restrict__ x,
                                       const float* __restrict__ dinv,
                                       _Float16* __restrict__ v0,
                                       _Float16* __restrict__ x16,
                                       _Float16* __restrict__ v1,
                                       _Float16* __restrict__ v3,
                                       _Float16* __restrict__ v7,
                                       _Float16* __restrict__ T1,
                                       _Float16* __restrict__ T2, int N) {
    int t = blockIdx.x * blockDim.x + threadIdx.x;
    if (t < N * 16) {
        int n = t >> 4, d4 = (t & 15) * 4;
        float d = dinv[n];
        float4 a = *(const float4*)(x + (size_t)n * DIM + d4);
        half4 hx;
        hx.x = (_Float16)a.x; hx.y = (_Float16)a.y;
        hx.z = (_Float16)a.z; hx.w = (_Float16)a.w;
        *(half4*)(x16 + (size_t)n * DIM + d4) = hx;
        half4 hv;
        hv.x = (_Float16)(a.x * d); hv.y = (_Float16)(a.y * d);
        hv.z = (_Float16)(a.z * d); hv.w = (_Float16)(a.w * d);
        int S = d4 >> 4, off = d4 & 15;
        *(half4*)(v0 + ((size_t)S * (N + 1) + n) * 16 + off) = hv;
    } else {
        int extra = t - N * 16;      // 96 half4 slots: 6 buffers x 64 halves
        if (extra < 96) {
            _Float16* bufs[6] = {v0, v1, v3, v7, T1, T2};
            int bf = extra >> 4;
            int r = (extra & 15) * 4;
            int S = r >> 4, off = r & 15;
            half4 z = {(_Float16)0.f, (_Float16)0.f,
                       (_Float16)0.f, (_Float16)0.f};
            *(half4*)(bufs[bf] + ((size_t)S * (N + 1) + N) * 16 + off) = z;
        }
    }
}

// ---------------------------------------------------------------------------
// Slab-major propagate v4: L2-RESIDENT slabs (4 slabs of 32B rows, XCD-pair
// pinned: slab = (blockIdx&7)>>1 -> 3.2 MB vin per XCD < 4 MB L2). R13's
// miss-bound diagnosis: 106 MB FETCH/pass = ~6.5K misses/CU, miss-service
// capacity is the wall (per-wave work changes were null). This trades TA
// (32 lines/gather vs 16) for ~zero gather misses.
// Wave = 8 nodes x 4 slots x 2 chunks of 16B. Straight-line 6-group preload
// + 2-step reduce (xor 2,4) kept from R13. Padding x4.
// ---------------------------------------------------------------------------
__launch_bounds__(256)
__global__ void spmv_slab_kernel(const int* __restrict__ ptr,
                                 const int* __restrict__ srcs,
                                 const float* __restrict__ dinv,
                                 const _Float16* __restrict__ vin,
                                 _Float16* __restrict__ vout,
                                 int N, int bps) {
    int b = blockIdx.x;
    int S   = (b & 7) >> 1;                  // XCD pair -> slab (0..3)
    int blk = ((b >> 3) << 1) | (b & 1);     // index within slab
    if (blk >= bps) return;
    const _Float16* vi = vin + (size_t)S * (N + 1) * 16;
    _Float16* vo = vout + (size_t)S * (N + 1) * 16;
    int tid = threadIdx.x;
    int lane = tid & 63;
    int nq = lane >> 3;           // node 0..7 within wave
    int e  = (lane >> 1) & 3;     // edge slot 0..3
    int hc = (lane & 1) << 3;     // 16B chunk of the 32B row (half offset)
    int n = blk * 32 + (tid >> 6) * 8 + nq;
    bool valid = n < N;

    // phase 0: independent per-node loads
    int beg = valid ? ptr[n] : 0;
    int end = valid ? ptr[n + 1] : 0;
    float d = valid ? dinv[n] : 0.f;

    // phase 1: group indices 0..5 preloaded (6 srcs loads in flight)
    int s0 = srcs[beg + e];
    int s1 = srcs[beg + 4 + e];
    int s2 = srcs[beg + 8 + e];
    int s3 = srcs[beg + 12 + e];
    int s4 = srcs[beg + 16 + e];
    int s5 = srcs[beg + 20 + e];

    // phase 2: unconditional group 0..3 gathers (4 in flight; indices are
    // always valid node ids thanks to tail pad, masking is arithmetic only)
    half8 h0 = *(const half8*)(vi + ((size_t)s0 << 4) + hc);
    half8 h1 = *(const half8*)(vi + ((size_t)s1 << 4) + hc);
    half8 h2 = *(const half8*)(vi + ((size_t)s2 << 4) + hc);
    half8 h3 = *(const half8*)(vi + ((size_t)s3 << 4) + hc);

    half8 z;
    #pragma unroll
    for (int k = 0; k < 8; ++k) z[k] = (_Float16)0.f;

    bool m1 = (beg + 8  <= end);
    bool m2 = (beg + 12 <= end);
    bool m3 = (beg + 16 <= end);
    half8 t01 = h0 + (m1 ? h1 : z);            // fp16 pk_add tree (depth 2)
    half8 t23 = (m2 ? h2 : z) + (m3 ? h3 : z);
    half8 g = t01 + t23;

    float a[8];
    #pragma unroll
    for (int k = 0; k < 8; ++k) a[k] = (float)g[k];

    // groups 4/5 (66% / 25% of nodes), then rare loop (6%)
    if (beg + 20 <= end) {
        half8 h4 = *(const half8*)(vi + ((size_t)s4 << 4) + hc);
        #pragma unroll
        for (int k = 0; k < 8; ++k) a[k] += (float)h4[k];
        if (beg + 24 <= end) {
            half8 h5 = *(const half8*)(vi + ((size_t)s5 << 4) + hc);
            #pragma unroll
            for (int k = 0; k < 8; ++k) a[k] += (float)h5[k];
            for (int j = beg + 24; j + 4 <= end; j += 4) {
                int s = srcs[j + e];
                half8 hx = *(const half8*)(vi + ((size_t)s << 4) + hc);
                #pragma unroll
                for (int k = 0; k < 8; ++k) a[k] += (float)hx[k];
            }
        }
    }

    // reduce across the 4 edge slots (lane bits 1,2): 2 steps
    #pragma unroll
    for (int k = 0; k < 8; ++k) {
        a[k] += __shfl_xor(a[k], 2);
        a[k] += __shfl_xor(a[k], 4);
    }
    if (e == 0 && valid) {
        float dd = d * d;
        half8 r;
        #pragma unroll
        for (int k = 0; k < 8; ++k)
            r[k] = (_Float16)(dd * a[k]);
        *(half8*)(vo + ((size_t)n << 4) + hc) = r;
    }
}

// ---------------------------------------------------------------------------
// make_wfrag: folded effective weights, fp16, in exact MFMA B-fragment order
// wf[((dt*8 + t)*64 + lane)*8 + j]  (lane = quad*16+col), so each combine
// B-load is one fully-coalesced 1 KB wave read of a 32 KB L1/L2-hot table.
// Fold (reference quirk: powers cumulative -> x_agg = {x, Ax, A^3x, A^7x}):
//   cat@W = x@W3 + p1@(W0-W3+W4) + p3@(W1-W4+W5) + p7@(W2-W5)
// ---------------------------------------------------------------------------
__global__ void make_wfrag_kernel(const float* __restrict__ W,
                                  _Float16* __restrict__ wf) {
    int idx = blockIdx.x * blockDim.x + threadIdx.x;   // 16384
    if (idx < 16384) {
        int j = idx & 7;
        int lane = (idx >> 3) & 63;
        int t = (idx >> 9) & 7;
        int dt = idx >> 12;
        int col = lane & 15, quad = lane >> 4;
        int d = dt * 16 + col;
        int kk = t * 32 + quad * 8 + j;
        int src = kk >> 6, k = kk & 63;
        float v;
        if (src == 0)      v = W[(3 * 64 + k) * 64 + d];
        else if (src == 1) v = W[(0 * 64 + k) * 64 + d]
                             - W[(3 * 64 + k) * 64 + d]
                             + W[(4 * 64 + k) * 64 + d];
        else if (src == 2) v = W[(1 * 64 + k) * 64 + d]
                             - W[(4 * 64 + k) * 64 + d]
                             + W[(5 * 64 + k) * 64 + d];
        else               v = W[(2 * 64 + k) * 64 + d]
                             - W[(5 * 64 + k) * 64 + d];
        wf[idx] = (_Float16)v;
    }
}

// ---------------------------------------------------------------------------
// MFMA combine: no LDS, no syncthreads. A-fragments direct from global
// (half8 in A-layout, rdinv applied as fp16 scale); B-fragments direct from
// the 32 KB fragment-ordered wf table. One wave = one 16-node group, all 64
// output dims (32 mfma). vs slab addressing: slab = d0>>4, off = d0&15.
// ---------------------------------------------------------------------------
__launch_bounds__(256)
__global__ void combine_mfma_kernel(const _Float16* __restrict__ x16,
                                    const _Float16* __restrict__ v1,
                                    const _Float16* __restrict__ v3,
                                    const _Float16* __restrict__ v7,
                                    const float* __restrict__ rdinv,
                                    const _Float16* __restrict__ wf,
                                    const float* __restrict__ bias,
                                    float* __restrict__ out, int N) {
    int tid = threadIdx.x;
    int lane = tid & 63, w = tid >> 6;
    int quad = lane >> 4, col = lane & 15;

    float bv[4];
    #pragma unroll
    for (int dt = 0; dt < 4; ++dt) bv[dt] = bias[dt * 16 + col];

    int bps = (N + 15) / 16;
    size_t N1 = (size_t)N + 1;
    for (int g = blockIdx.x * 4 + w; g < bps; g += gridDim.x * 4) {
        int n0 = g * 16;
        int n = n0 + col;
        int nl = (n < N) ? n : 0;
        _Float16 hrd = (_Float16)rdinv[nl];

        half8 a[8];
        a[0] = *(const half8*)(x16 + (size_t)nl * DIM + quad * 8);
        a[1] = *(const half8*)(x16 + (size_t)nl * DIM + 32 + quad * 8);
        const _Float16* vs[3] = {v1, v3, v7};
        #pragma unroll
        for (int sI = 0; sI < 3; ++sI) {
            #pragma unroll
            for (int hf = 0; hf < 2; ++hf) {
                int d0 = hf * 32 + quad * 8;
                int sl = d0 >> 4, off = d0 & 15;
                half8 hv = *(const half8*)(vs[sI] + ((size_t)sl * N1 + nl) * 16 + off);
                #pragma unroll
                for (int j = 0; j < 8; ++j) hv[j] = hv[j] * hrd;
                a[2 + sI * 2 + hf] = hv;
            }
        }

        floatx4 acc[4];
        #pragma unroll
        for (int dt = 0; dt < 4; ++dt) {
            floatx4 z = {bv[dt], bv[dt], bv[dt], bv[dt]};
            acc[dt] = z;
        }
        #pragma unroll
        for (int t = 0; t < 8; ++t) {
            #pragma unroll
            for (int dt = 0; dt < 4; ++dt) {
                half8 bf = *(const half8*)(wf + (((dt * 8 + t) * 64 + lane) << 3));
                acc[dt] = __builtin_amdgcn_mfma_f32_16x16x32_f16(
                    a[t], bf, acc[dt], 0, 0, 0);
            }
        }

        #pragma unroll
        for (int dt = 0; dt < 4; ++dt)
            #pragma unroll
            for (int r = 0; r < 4; ++r) {
                int nn = n0 + quad * 4 + r;
                if (nn < N)
                    out[(size_t)nn * DIM + dt * 16 + col] =
                        fmaxf(acc[dt][r], 0.f);
            }
    }
}

extern "C" void kernel_launch(void* const* d_in, const int* in_sizes, int n_in,
                              void* d_out, int out_size, void* d_ws, size_t ws_size,
                              hipStream_t stream) {
    const float* x  = (const float*)d_in[0];
    const int*   ei = (const int*)d_in[1];
    const float* W  = (const float*)d_in[2];
    const float* b  = (const float*)d_in[3];
    float* out = (float*)d_out;

    const int N = in_sizes[0] / DIM;
    const int E = in_sizes[1] / 2;
    const int* row = ei;
    const int* col = ei + E;

    const int nbins = (N + 255) >> BIN_SHIFT;
    int sbps = (N + 31) / 32;             // blocks per slab (32 nodes/blk)
    if (sbps & 1) ++sbps;                 // even for the swizzle bijection
    const size_t SLABSZ = (size_t)4 * (N + 1) * 16;   // halves per buffer

    int2* staging = (int2*)d_ws;                          // 512*BCAP
    float* dinv  = (float*)(staging + (size_t)512 * BCAP);
    float* rdinv = dinv + N;
    _Float16* wf  = (_Float16*)(rdinv + N);               // 16384 halves
    _Float16* x16 = wf + 16384;                           // (N+16)*64
    _Float16* v0 = x16 + (size_t)(N + 16) * 64;
    _Float16* v1 = v0 + SLABSZ;
    _Float16* v3 = v1 + SLABSZ;
    _Float16* v7 = v3 + SLABSZ;
    _Float16* T1 = v7 + SLABSZ;
    _Float16* T2 = T1 + SLABSZ;
    int* deg = (int*)(T2 + SLABSZ);       // N
    int* ptr = deg + N;                   // N+1
    int* bs  = ptr + N + 1;               // <=1024
    int* bin_cursor = bs + 1024;          // 512
    int* srcs = bin_cursor + 512;         // E + 4N + 64 tail pad

    // --- bin edges ---
    hipMemsetAsync(bin_cursor, 0, 512 * sizeof(int), stream);
    bin_edges_kernel<<<(E + 4095) / 4096, 256, 0, stream>>>(row, col,
                                                            bin_cursor,
                                                            staging, E);
    // --- per-bin degree + dinv/rdinv + padded chunk sums ---
    count_deg_bins_kernel<<<nbins, 256, 0, stream>>>(staging, bin_cursor,
                                                     deg, dinv, rdinv, bs, N);
    // --- scan of chunk sums, then per-chunk prefix -> ptr ---
    scan_block_sums_kernel<<<1, 1024, 0, stream>>>(bs, nbins);
    scan_chunks_kernel<<<nbins, 256, 0, stream>>>(deg, bs, ptr, N);
    // --- CSC fill from bins (self-edge + edges + dummy pads + tail pad) ---
    fill_bins_kernel<<<nbins, 256, 0, stream>>>(staging, bin_cursor, ptr,
                                                srcs, N, N);
    // --- fragment-ordered folded weights ---
    make_wfrag_kernel<<<64, 256, 0, stream>>>(W, wf);
    // --- v0 (4-slab-major) + x16 + dummy-row zeroing ---
    scale_init_slab_kernel<<<(N * 16 + 96 + 255) / 256, 256, 0, stream>>>(
        x, dinv, v0, x16, v1, v3, v7, T1, T2, N);

    auto prop = [&](const _Float16* src, _Float16* dst) {
        spmv_slab_kernel<<<4 * sbps, 256, 0, stream>>>(ptr, srcs, dinv,
                                                       src, dst, N, sbps);
    };
    prop(v0, v1);   // A^1
    prop(v1, T1);   // A^2
    prop(T1, v3);   // A^3
    prop(v3, T1);   // A^4
    prop(T1, T2);   // A^5
    prop(T2, T1);   // A^6
    prop(T1, v7);   // A^7

    // --- combine (MFMA, fragment-table B, direct A loads, no LDS) ---
    combine_mfma_kernel<<<1024, 256, 0, stream>>>(x16, v1, v3, v7, rdinv,
                                                  wf, b, out, N);
}

// Round 16
// 400.306 us; speedup vs baseline: 1.0865x; 1.0865x over previous
//
#include <hip/hip_runtime.h>

#define DIM 64
#define BIN_SHIFT 8          // 256 nodes per bin
#define BCAP 5120            // staging capacity per bin (mean 4092, +16 sigma)

typedef __attribute__((ext_vector_type(8))) _Float16 half8;
typedef __attribute__((ext_vector_type(4))) _Float16 half4;
typedef __attribute__((ext_vector_type(4))) float floatx4;

// ---------------------------------------------------------------------------
// Binning pass A: per-block 512-bin histogram of col>>8 -> blockhist.
// Deterministic radix structure replaces the global-atomic reservation that
// kept bin_edges at ~38us (VALU 1.7%: atomic contention on 512 hot words).
// ---------------------------------------------------------------------------
__launch_bounds__(256)
__global__ void hist_kernel(const int* __restrict__ col,
                            int* __restrict__ blockhist, int E) {
    __shared__ int hist[512];
    int tid = threadIdx.x;
    for (int i = tid; i < 512; i += 256) hist[i] = 0;
    __syncthreads();
    int e0 = blockIdx.x * 4096;
    #pragma unroll
    for (int k = 0; k < 16; ++k) {
        int e = e0 + tid + k * 256;
        if (e < E) atomicAdd(&hist[col[e] >> BIN_SHIFT], 1);
    }
    __syncthreads();
    for (int i = tid; i < 512; i += 256)
        blockhist[(size_t)blockIdx.x * 512 + i] = hist[i];
}

// ---------------------------------------------------------------------------
// Binning pass B: one block per bin; exclusive scan of blockhist over the
// (up to 512) edge-blocks -> per-(block,bin) base offsets, and bin totals ->
// bin_cursor (replaces memset + atomic reservation).
// ---------------------------------------------------------------------------
__global__ void scan_hist_kernel(const int* __restrict__ blockhist,
                                 int* __restrict__ offs_g,
                                 int* __restrict__ bin_cursor, int nb) {
    __shared__ int s[256];
    int bin = blockIdx.x, t = threadIdx.x;
    int h0 = (2 * t < nb)     ? blockhist[(size_t)(2 * t) * 512 + bin]     : 0;
    int h1 = (2 * t + 1 < nb) ? blockhist[(size_t)(2 * t + 1) * 512 + bin] : 0;
    int ps = h0 + h1;
    s[t] = ps;
    __syncthreads();
    for (int d = 1; d < 256; d <<= 1) {
        int v = (t >= d) ? s[t - d] : 0;
        __syncthreads();
        s[t] += v;
        __syncthreads();
    }
    int ex = s[t] - ps;
    if (2 * t < nb)     offs_g[(size_t)(2 * t) * 512 + bin] = ex;
    if (2 * t + 1 < nb) offs_g[(size_t)(2 * t + 1) * 512 + bin] = ex + h0;
    if (t == 255) bin_cursor[bin] = s[255];
}

// ---------------------------------------------------------------------------
// Binning pass C: in-block counting sort by bin in LDS (R5 structure), but
// base offsets are READ from offs_g (deterministic) -- zero global atomics.
// Bin-sorted readout -> contiguous store runs per bin segment.
// ---------------------------------------------------------------------------
__launch_bounds__(256)
__global__ void scatter_edges_kernel(const int* __restrict__ row,
                                     const int* __restrict__ col,
                                     const int* __restrict__ offs_g,
                                     int2* __restrict__ staging, int E) {
    __shared__ int hist[512];
    __shared__ int offs[512];
    __shared__ int base[512];
    __shared__ int s[256];
    __shared__ int2 buf[4096];
    int tid = threadIdx.x;
    for (int i = tid; i < 512; i += 256) hist[i] = 0;
    __syncthreads();
    int e0 = blockIdx.x * 4096;
    int c[16], r[16];
    #pragma unroll
    for (int k = 0; k < 16; ++k) {
        int e = e0 + tid + k * 256;
        c[k] = (e < E) ? col[e] : -1;
        r[k] = (e < E) ? row[e] : 0;
        if (c[k] >= 0) atomicAdd(&hist[c[k] >> BIN_SHIFT], 1);
    }
    __syncthreads();
    // exclusive scan of hist[512] via pair-sums + Hillis-Steele over 256
    int h0 = hist[2 * tid], h1 = hist[2 * tid + 1];
    int ps = h0 + h1;
    s[tid] = ps;
    __syncthreads();
    for (int d = 1; d < 256; d <<= 1) {
        int v = (tid >= d) ? s[tid - d] : 0;
        __syncthreads();
        s[tid] += v;
        __syncthreads();
    }
    int ex = s[tid] - ps;
    offs[2 * tid] = ex;
    offs[2 * tid + 1] = ex + h0;
    __syncthreads();
    // deterministic per-(block,bin) base; reset hist as scatter cursor
    for (int i = tid; i < 512; i += 256) {
        base[i] = offs_g[(size_t)blockIdx.x * 512 + i];
        hist[i] = 0;
    }
    __syncthreads();
    // scatter into bin-sorted LDS buffer
    #pragma unroll
    for (int k = 0; k < 16; ++k) {
        if (c[k] >= 0) {
            int b = c[k] >> BIN_SHIFT;
            int pos = offs[b] + atomicAdd(&hist[b], 1);
            buf[pos] = make_int2(r[k], c[k]);
        }
    }
    __syncthreads();
    // linear readout: adjacent lanes -> adjacent buf -> contiguous store runs
    int count = (e0 + 4096 <= E) ? 4096 : (E > e0 ? E - e0 : 0);
    for (int i = tid; i < count; i += 256) {
        int2 rc = buf[i];
        int b = rc.y >> BIN_SHIFT;
        staging[(size_t)b * BCAP + base[b] + (i - offs[b])] = rc;
    }
}

// ---------------------------------------------------------------------------
// Per-bin degree count + dinv/rdinv + padded chunk sum bs[b].
// pdeg = (deg+1+3)&~3  (self-edge included, pad to groups of 4).
// ---------------------------------------------------------------------------
__launch_bounds__(256)
__global__ void count_deg_bins_kernel(const int2* __restrict__ staging,
                                      const int* __restrict__ bin_cursor,
                                      int* __restrict__ deg,
                                      float* __restrict__ dinv,
                                      float* __restrict__ rdinv,
                                      int* __restrict__ bs, int N) {
    __shared__ int hist[256];
    __shared__ int red[256];
    int b = blockIdx.x;
    int tid = threadIdx.x;
    hist[tid] = 0;
    __syncthreads();
    int cnt = bin_cursor[b];
    for (int i = tid; i < cnt; i += 256)
        atomicAdd(&hist[staging[(size_t)b * BCAP + i].y & 255], 1);
    __syncthreads();
    int n = (b << BIN_SHIFT) + tid;
    int pdeg = 0;
    if (n < N) {
        int dg = hist[tid];
        deg[n] = dg;
        float d = (float)dg + 1.0f;
        dinv[n] = rsqrtf(d);
        rdinv[n] = sqrtf(d);
        pdeg = (dg + 1 + 3) & ~3;
    }
    red[tid] = pdeg;
    __syncthreads();
    for (int d = 128; d > 0; d >>= 1) {
        if (tid < d) red[tid] += red[tid + d];
        __syncthreads();
    }
    if (tid == 0) bs[b] = red[0];
}

__global__ void scan_block_sums_kernel(int* __restrict__ bs, int nb) {
    __shared__ int s[1024];
    int t = threadIdx.x;
    s[t] = (t < nb) ? bs[t] : 0;
    __syncthreads();
    for (int d = 1; d < 1024; d <<= 1) {
        int v = (t >= d) ? s[t - d] : 0;
        __syncthreads();
        s[t] += v;
        __syncthreads();
    }
    if (t < nb) bs[t] = (t == 0) ? 0 : s[t - 1];
}

__global__ void scan_chunks_kernel(const int* __restrict__ deg,
                                   const int* __restrict__ bs,
                                   int* __restrict__ ptr, int N) {
    __shared__ int s[256];
    int b = blockIdx.x, t = threadIdx.x;
    int i = b * 256 + t;
    int v = (i < N) ? ((deg[i] + 1 + 3) & ~3) : 0;
    s[t] = v;
    __syncthreads();
    for (int d = 1; d < 256; d <<= 1) {
        int u = (t >= d) ? s[t - d] : 0;
        __syncthreads();
        s[t] += u;
        __syncthreads();
    }
    if (i < N) {
        int p = bs[b] + s[t] - v;
        ptr[i] = p;
        if (i == N - 1) ptr[N] = p + v;
    }
}

// ---------------------------------------------------------------------------
// Pass B: one block per bin; LDS cursors. Bucket = self-edge n, in-edges,
// dummy-N padding to x4. Last block also fills the 64-int srcs tail pad with
// dummy (spmv speculatively preloads group indices up to beg+23).
// ---------------------------------------------------------------------------
__launch_bounds__(256)
__global__ void fill_bins_kernel(const int2* __restrict__ staging,
                                 const int* __restrict__ bin_cursor,
                                 const int* __restrict__ ptr,
                                 int* __restrict__ srcs, int N, int dummy) {
    __shared__ int cur[256];
    int b = blockIdx.x;
    int tid = threadIdx.x;
    int n = (b << BIN_SHIFT) + tid;
    if (n < N) {
        int p = ptr[n];
        srcs[p] = n;           // self-edge
        cur[tid] = p + 1;
    } else cur[tid] = 0;
    if (b == gridDim.x - 1 && tid < 64)
        srcs[ptr[N] + tid] = dummy;      // tail pad: valid (zero) row ids
    __syncthreads();
    int cnt = bin_cursor[b];
    for (int i = tid; i < cnt; i += 256) {
        int2 rc = staging[(size_t)b * BCAP + i];
        int pos = atomicAdd(&cur[rc.y & 255], 1);
        srcs[pos] = rc.x;
    }
    __syncthreads();
    if (n < N) {
        int e = cur[tid];            // == ptr[n] + 1 + deg[n]
        int stop = ptr[n + 1];
        for (; e < stop; ++e) srcs[e] = dummy;
    }
}

// ---------------------------------------------------------------------------
// scale_init: v0 (superslab-major fp16 = dinv*x), x16 (row-major fp16), and
// dummy-row zeroing for all 6 superslab buffers (tail threads).
// Superslab S = d>>5 (32 halves = 64B per row), row n at (S*(N+1)+n)*32.
// R13 geometry: 64B rows = full line utilization (2 lines/edge, the minimum).
// ---------------------------------------------------------------------------
__global__ void scale_init_slab_kernel(const float* __restrict__ x,
                                       const float* __restrict__ dinv,
                                       _Float16* __restrict__ v0,
                                       _Float16* __restrict__ x16,
                                       _Float16* __restrict__ v1,
                                       _Float16* __restrict__ v3,
                                       _Float16* __restrict__ v7,
                                       _Float16* __restrict__ T1,
                                       _Float16* __restrict__ T2, int N) {
    int t = blockIdx.x * blockDim.x + threadIdx.x;
    if (t < N * 16) {
        int n = t >> 4, d4 = (t & 15) * 4;
        float d = dinv[n];
        float4 a = *(const float4*)(x + (size_t)n * DIM + d4);
        half4 hx;
        hx.x = (_Float16)a.x; hx.y = (_Float16)a.y;
        hx.z = (_Float16)a.z; hx.w = (_Float16)a.w;
        *(half4*)(x16 + (size_t)n * DIM + d4) = hx;
        half4 hv;
        hv.x = (_Float16)(a.x * d); hv.y = (_Float16)(a.y * d);
        hv.z = (_Float16)(a.z * d); hv.w = (_Float16)(a.w * d);
        int S = d4 >> 5, off = d4 & 31;
        *(half4*)(v0 + ((size_t)S * (N + 1) + n) * 32 + off) = hv;
    } else {
        int extra = t - N * 16;      // 96 half4 slots: 6 buffers x 64 halves
        if (extra < 96) {
            _Float16* bufs[6] = {v0, v1, v3, v7, T1, T2};
            int bf = extra >> 4;
            int r = (extra & 15) * 4;
            int S = r >> 5, off = r & 31;
            half4 z = {(_Float16)0.f, (_Float16)0.f,
                       (_Float16)0.f, (_Float16)0.f};
            *(half4*)(bufs[bf] + ((size_t)S * (N + 1) + N) * 32 + off) = z;
        }
    }
}

// ---------------------------------------------------------------------------
// Superslab-major propagate (R13, best measured): 4-slot lanes (wave =
// 4 nodes x 4 slots x 4 chunks of 16B over 64B rows). Straight-line 6-group
// preload, x4 padding, 2-step reduce (xor 4,8). XCD-quad pinning:
// superslab S = (blockIdx&7)>>2. R15 proved 32B rows (half-line waste) cost
// +4us despite zero misses -> 64B rows are line-optimal; keep.
// ---------------------------------------------------------------------------
__launch_bounds__(256)
__global__ void spmv_slab_kernel(const int* __restrict__ ptr,
                                 const int* __restrict__ srcs,
                                 const float* __restrict__ dinv,
                                 const _Float16* __restrict__ vin,
                                 _Float16* __restrict__ vout,
                                 int N, int bps) {
    int b = blockIdx.x;
    int S   = (b & 7) >> 2;                  // XCD quad -> superslab
    int blk = ((b >> 3) << 2) | (b & 3);     // index within superslab
    if (blk >= bps) return;
    const _Float16* vi = vin + (size_t)S * (N + 1) * 32;
    _Float16* vo = vout + (size_t)S * (N + 1) * 32;
    int tid = threadIdx.x;
    int lane = tid & 63;
    int nq = (lane >> 4) & 3;     // node 0..3 within wave
    int e  = (lane >> 2) & 3;     // edge slot 0..3
    int hc = (lane & 3) << 3;     // 16B chunk of the 64B row (half offset)
    int n = blk * 16 + (tid >> 6) * 4 + nq;
    bool valid = n < N;

    // phase 0: independent per-node loads
    int beg = valid ? ptr[n] : 0;
    int end = valid ? ptr[n + 1] : 0;
    float d = valid ? dinv[n] : 0.f;

    // phase 1: group indices 0..5 preloaded (6 srcs loads in flight)
    int s0 = srcs[beg + e];
    int s1 = srcs[beg + 4 + e];
    int s2 = srcs[beg + 8 + e];
    int s3 = srcs[beg + 12 + e];
    int s4 = srcs[beg + 16 + e];
    int s5 = srcs[beg + 20 + e];

    // phase 2: unconditional group 0..3 gathers (4 in flight; indices are
    // always valid node ids thanks to tail pad, masking is arithmetic only)
    half8 h0 = *(const half8*)(vi + ((size_t)s0 << 5) + hc);
    half8 h1 = *(const half8*)(vi + ((size_t)s1 << 5) + hc);
    half8 h2 = *(const half8*)(vi + ((size_t)s2 << 5) + hc);
    half8 h3 = *(const half8*)(vi + ((size_t)s3 << 5) + hc);

    half8 z;
    #pragma unroll
    for (int k = 0; k < 8; ++k) z[k] = (_Float16)0.f;

    bool m1 = (beg + 8  <= end);
    bool m2 = (beg + 12 <= end);
    bool m3 = (beg + 16 <= end);
    half8 t01 = h0 + (m1 ? h1 : z);            // fp16 pk_add tree (depth 2)
    half8 t23 = (m2 ? h2 : z) + (m3 ? h3 : z);
    half8 g = t01 + t23;

    float a[8];
    #pragma unroll
    for (int k = 0; k < 8; ++k) a[k] = (float)g[k];

    // groups 4/5 (66% / 25% of nodes), then rare loop (6%)
    if (beg + 20 <= end) {
        half8 h4 = *(const half8*)(vi + ((size_t)s4 << 5) + hc);
        #pragma unroll
        for (int k = 0; k < 8; ++k) a[k] += (float)h4[k];
        if (beg + 24 <= end) {
            half8 h5 = *(const half8*)(vi + ((size_t)s5 << 5) + hc);
            #pragma unroll
            for (int k = 0; k < 8; ++k) a[k] += (float)h5[k];
            for (int j = beg + 24; j + 4 <= end; j += 4) {
                int s = srcs[j + e];
                half8 hx = *(const half8*)(vi + ((size_t)s << 5) + hc);
                #pragma unroll
                for (int k = 0; k < 8; ++k) a[k] += (float)hx[k];
            }
        }
    }

    // reduce across the 4 edge slots (lane bits 2,3): 2 steps
    #pragma unroll
    for (int k = 0; k < 8; ++k) {
        a[k] += __shfl_xor(a[k], 4);
        a[k] += __shfl_xor(a[k], 8);
    }
    if (e == 0 && valid) {
        float dd = d * d;
        half8 r;
        #pragma unroll
        for (int k = 0; k < 8; ++k)
            r[k] = (_Float16)(dd * a[k]);
        *(half8*)(vo + ((size_t)n << 5) + hc) = r;
    }
}

// ---------------------------------------------------------------------------
// make_wfrag: folded effective weights, fp16, in exact MFMA B-fragment order
// wf[((dt*8 + t)*64 + lane)*8 + j]  (lane = quad*16+col), so each combine
// B-load is one fully-coalesced 1 KB wave read of a 32 KB L1/L2-hot table.
// Fold (reference quirk: powers cumulative -> x_agg = {x, Ax, A^3x, A^7x}):
//   cat@W = x@W3 + p1@(W0-W3+W4) + p3@(W1-W4+W5) + p7@(W2-W5)
// ---------------------------------------------------------------------------
__global__ void make_wfrag_kernel(const float* __restrict__ W,
                                  _Float16* __restrict__ wf) {
    int idx = blockIdx.x * blockDim.x + threadIdx.x;   // 16384
    if (idx < 16384) {
        int j = idx & 7;
        int lane = (idx >> 3) & 63;
        int t = (idx >> 9) & 7;
        int dt = idx >> 12;
        int col = lane & 15, quad = lane >> 4;
        int d = dt * 16 + col;
        int kk = t * 32 + quad * 8 + j;
        int src = kk >> 6, k = kk & 63;
        float v;
        if (src == 0)      v = W[(3 * 64 + k) * 64 + d];
        else if (src == 1) v = W[(0 * 64 + k) * 64 + d]
                             - W[(3 * 64 + k) * 64 + d]
                             + W[(4 * 64 + k) * 64 + d];
        else if (src == 2) v = W[(1 * 64 + k) * 64 + d]
                             - W[(4 * 64 + k) * 64 + d]
                             + W[(5 * 64 + k) * 64 + d];
        else               v = W[(2 * 64 + k) * 64 + d]
                             - W[(5 * 64 + k) * 64 + d];
        wf[idx] = (_Float16)v;
    }
}

// ---------------------------------------------------------------------------
// MFMA combine: no LDS, no syncthreads. A-fragments direct from global
// (half8 in A-layout, rdinv applied as fp16 scale); B-fragments direct from
// the 32 KB fragment-ordered wf table. One wave = one 16-node group, all 64
// output dims (32 mfma). Superslab addressing: S = d0>>5, off = d0&31.
// ---------------------------------------------------------------------------
__launch_bounds__(256)
__global__ void combine_mfma_kernel(const _Float16* __restrict__ x16,
                                    const _Float16* __restrict__ v1,
                                    const _Float16* __restrict__ v3,
                                    const _Float16* __restrict__ v7,
                                    const float* __restrict__ rdinv,
                                    const _Float16* __restrict__ wf,
                                    const float* __restrict__ bias,
                                    float* __restrict__ out, int N) {
    int tid = threadIdx.x;
    int lane = tid & 63, w = tid >> 6;
    int quad = lane >> 4, col = lane & 15;

    float bv[4];
    #pragma unroll
    for (int dt = 0; dt < 4; ++dt) bv[dt] = bias[dt * 16 + col];

    int bps = (N + 15) / 16;
    size_t N1 = (size_t)N + 1;
    for (int g = blockIdx.x * 4 + w; g < bps; g += gridDim.x * 4) {
        int n0 = g * 16;
        int n = n0 + col;
        int nl = (n < N) ? n : 0;
        _Float16 hrd = (_Float16)rdinv[nl];

        half8 a[8];
        a[0] = *(const half8*)(x16 + (size_t)nl * DIM + quad * 8);
        a[1] = *(const half8*)(x16 + (size_t)nl * DIM + 32 + quad * 8);
        const _Float16* vs[3] = {v1, v3, v7};
        #pragma unroll
        for (int sI = 0; sI < 3; ++sI) {
            #pragma unroll
            for (int hf = 0; hf < 2; ++hf) {
                // d0 = hf*32 + quad*8  ->  superslab S = hf, offset quad*8
                half8 hv = *(const half8*)(vs[sI] + ((size_t)hf * N1 + nl) * 32 + quad * 8);
                #pragma unroll
                for (int j = 0; j < 8; ++j) hv[j] = hv[j] * hrd;
                a[2 + sI * 2 + hf] = hv;
            }
        }

        floatx4 acc[4];
        #pragma unroll
        for (int dt = 0; dt < 4; ++dt) {
            floatx4 z = {bv[dt], bv[dt], bv[dt], bv[dt]};
            acc[dt] = z;
        }
        #pragma unroll
        for (int t = 0; t < 8; ++t) {
            #pragma unroll
            for (int dt = 0; dt < 4; ++dt) {
                half8 bf = *(const half8*)(wf + (((dt * 8 + t) * 64 + lane) << 3));
                acc[dt] = __builtin_amdgcn_mfma_f32_16x16x32_f16(
                    a[t], bf, acc[dt], 0, 0, 0);
            }
        }

        #pragma unroll
        for (int dt = 0; dt < 4; ++dt)
            #pragma unroll
            for (int r = 0; r < 4; ++r) {
                int nn = n0 + quad * 4 + r;
                if (nn < N)
                    out[(size_t)nn * DIM + dt * 16 + col] =
                        fmaxf(acc[dt][r], 0.f);
            }
    }
}

extern "C" void kernel_launch(void* const* d_in, const int* in_sizes, int n_in,
                              void* d_out, int out_size, void* d_ws, size_t ws_size,
                              hipStream_t stream) {
    const float* x  = (const float*)d_in[0];
    const int*   ei = (const int*)d_in[1];
    const float* W  = (const float*)d_in[2];
    const float* b  = (const float*)d_in[3];
    float* out = (float*)d_out;

    const int N = in_sizes[0] / DIM;
    const int E = in_sizes[1] / 2;
    const int* row = ei;
    const int* col = ei + E;

    const int nbins = (N + 255) >> BIN_SHIFT;
    const int nbE = (E + 4095) / 4096;    // edge blocks (<=512 assumed)
    int sbps = (N + 15) / 16;             // blocks per superslab (16 nodes/blk)
    sbps = (sbps + 3) & ~3;               // x4 for the swizzle bijection
    const size_t SLABSZ = (size_t)2 * (N + 1) * 32;   // halves per buffer

    int2* staging = (int2*)d_ws;                          // 512*BCAP
    float* dinv  = (float*)(staging + (size_t)512 * BCAP);
    float* rdinv = dinv + N;
    _Float16* wf  = (_Float16*)(rdinv + N);               // 16384 halves
    _Float16* x16 = wf + 16384;                           // (N+16)*64
    _Float16* v0 = x16 + (size_t)(N + 16) * 64;
    _Float16* v1 = v0 + SLABSZ;
    _Float16* v3 = v1 + SLABSZ;
    _Float16* v7 = v3 + SLABSZ;
    _Float16* T1 = v7 + SLABSZ;
    _Float16* T2 = T1 + SLABSZ;
    int* deg = (int*)(T2 + SLABSZ);       // N
    int* ptr = deg + N;                   // N+1
    int* bs  = ptr + N + 1;               // <=1024
    int* bin_cursor = bs + 1024;          // 512
    int* srcs = bin_cursor + 512;         // E + 4N + 64 tail pad
    int* blockhist = srcs + (size_t)E + 4 * (size_t)N + 64;  // 512*512
    int* offs_g = blockhist + (size_t)512 * 512;             // 512*512

    // --- binning: hist -> per-bin scan over blocks -> atomic-free scatter ---
    hist_kernel<<<nbE, 256, 0, stream>>>(col, blockhist, E);
    scan_hist_kernel<<<512, 256, 0, stream>>>(blockhist, offs_g,
                                              bin_cursor, nbE);
    scatter_edges_kernel<<<nbE, 256, 0, stream>>>(row, col, offs_g,
                                                  staging, E);
    // --- per-bin degree + dinv/rdinv + padded chunk sums ---
    count_deg_bins_kernel<<<nbins, 256, 0, stream>>>(staging, bin_cursor,
                                                     deg, dinv, rdinv, bs, N);
    // --- scan of chunk sums, then per-chunk prefix -> ptr ---
    scan_block_sums_kernel<<<1, 1024, 0, stream>>>(bs, nbins);
    scan_chunks_kernel<<<nbins, 256, 0, stream>>>(deg, bs, ptr, N);
    // --- CSC fill from bins (self-edge + edges + dummy pads + tail pad) ---
    fill_bins_kernel<<<nbins, 256, 0, stream>>>(staging, bin_cursor, ptr,
                                                srcs, N, N);
    // --- fragment-ordered folded weights ---
    make_wfrag_kernel<<<64, 256, 0, stream>>>(W, wf);
    // --- v0 (superslab-major) + x16 + dummy-row zeroing ---
    scale_init_slab_kernel<<<(N * 16 + 96 + 255) / 256, 256, 0, stream>>>(
        x, dinv, v0, x16, v1, v3, v7, T1, T2, N);

    auto prop = [&](const _Float16* src, _Float16* dst) {
        spmv_slab_kernel<<<2 * sbps, 256, 0, stream>>>(ptr, srcs, dinv,
                                                       src, dst, N, sbps);
    };
    prop(v0, v1);   // A^1
    prop(v1, T1);   // A^2
    prop(T1, v3);   // A^3
    prop(v3, T1);   // A^4
    prop(T1, T2);   // A^5
    prop(T2, T1);   // A^6
    prop(T1, v7);   // A^7

    // --- combine (MFMA, fragment-table B, direct A loads, no LDS) ---
    combine_mfma_kernel<<<1024, 256, 0, stream>>>(x16, v1, v3, v7, rdinv,
                                                  wf, b, out, N);
}